// Round 2
// baseline (4281.508 us; speedup 1.0000x reference)
//
#include <hip/hip_runtime.h>
#include <hip/hip_bf16.h>
#include <cstddef>

typedef __bf16 bf16_t;
typedef __bf16 bf16x8 __attribute__((ext_vector_type(8)));
typedef __bf16 bf16x4 __attribute__((ext_vector_type(4)));
typedef float f32x4 __attribute__((ext_vector_type(4)));

#define T_LEN 96
#define BATCH 64
#define DM 1024
#define NTB 6144  // T*B

__device__ __forceinline__ float sigmoidf_(float x) { return 1.0f / (1.0f + expf(-x)); }

// ---------------- LN2 stats: per (tensor i, batch b) mean & inv-std over T*DM ----------------
__global__ __launch_bounds__(256) void ln_stats_kernel(
    const float* __restrict__ r1, const float* __restrict__ r2,
    const float* __restrict__ r3, const float* __restrict__ r4,
    float* __restrict__ stats)  // [4*64][2]
{
    const int i = blockIdx.x >> 6, b = blockIdx.x & 63;
    const float* r = (i == 0) ? r1 : (i == 1) ? r2 : (i == 2) ? r3 : r4;
    float s = 0.f, ss = 0.f;
    for (int t = 0; t < T_LEN; ++t) {
        float4 v = ((const float4*)(r + (size_t)(t * BATCH + b) * DM))[threadIdx.x];
        s  += v.x + v.y + v.z + v.w;
        ss += v.x * v.x + v.y * v.y + v.z * v.z + v.w * v.w;
    }
    __shared__ float sh[512];
    sh[threadIdx.x] = s; sh[256 + threadIdx.x] = ss;
    __syncthreads();
    for (int off = 128; off > 0; off >>= 1) {
        if (threadIdx.x < off) {
            sh[threadIdx.x] += sh[threadIdx.x + off];
            sh[256 + threadIdx.x] += sh[256 + threadIdx.x + off];
        }
        __syncthreads();
    }
    if (threadIdx.x == 0) {
        const float inv = 1.0f / (float)(T_LEN * DM);
        float mean = sh[0] * inv;
        float var  = sh[256] * inv - mean * mean;
        stats[blockIdx.x * 2 + 0] = mean;
        stats[blockIdx.x * 2 + 1] = rsqrtf(var + 1e-5f);
    }
}

// ---------------- U = mean of 4 normalized tensors, written as bf16 [NTB,1024] ----------------
__global__ __launch_bounds__(256) void compute_u_kernel(
    const float* __restrict__ r1, const float* __restrict__ r2,
    const float* __restrict__ r3, const float* __restrict__ r4,
    const float* __restrict__ stats, bf16_t* __restrict__ U)
{
    const int idx4 = blockIdx.x * 256 + threadIdx.x;   // over NTB*1024/4
    const int b = (idx4 >> 8) & 63;                    // row = idx4/256, b = row&63
    const float m0 = stats[(0 * 64 + b) * 2], s0 = stats[(0 * 64 + b) * 2 + 1];
    const float m1 = stats[(1 * 64 + b) * 2], s1 = stats[(1 * 64 + b) * 2 + 1];
    const float m2 = stats[(2 * 64 + b) * 2], s2 = stats[(2 * 64 + b) * 2 + 1];
    const float m3 = stats[(3 * 64 + b) * 2], s3 = stats[(3 * 64 + b) * 2 + 1];
    float4 a = ((const float4*)r1)[idx4];
    float4 c = ((const float4*)r2)[idx4];
    float4 d = ((const float4*)r3)[idx4];
    float4 e = ((const float4*)r4)[idx4];
    bf16x4 o;
    o[0] = (bf16_t)(0.25f * ((a.x - m0) * s0 + (c.x - m1) * s1 + (d.x - m2) * s2 + (e.x - m3) * s3));
    o[1] = (bf16_t)(0.25f * ((a.y - m0) * s0 + (c.y - m1) * s1 + (d.y - m2) * s2 + (e.y - m3) * s3));
    o[2] = (bf16_t)(0.25f * ((a.z - m0) * s0 + (c.z - m1) * s1 + (d.z - m2) * s2 + (e.z - m3) * s3));
    o[3] = (bf16_t)(0.25f * ((a.w - m0) * s0 + (c.w - m1) * s1 + (d.w - m2) * s2 + (e.w - m3) * s3));
    ((bf16x4*)U)[idx4] = o;
}

// ---------------- f32 -> bf16 cast with optional K padding ----------------
__global__ __launch_bounds__(256) void cast_pad_kernel(
    const float* __restrict__ src, bf16_t* __restrict__ dst,
    int rows, int K, int Kpad)
{
    int idx = blockIdx.x * 256 + threadIdx.x;
    if (idx >= rows * Kpad) return;
    int r = idx / Kpad;
    int k = idx - r * Kpad;
    float v = (k < K) ? src[(size_t)r * K + k] : 0.f;
    dst[idx] = (bf16_t)v;
}

// ---------------- bf16 MFMA GEMM: C[M,N] = A[M,K] @ W[N,K]^T + bias ----------------
#define GLDP 40  // LDS row pitch in bf16 (32 + 8 pad)
__global__ __launch_bounds__(256) void gemm_bt_kernel(
    const bf16_t* __restrict__ A, const bf16_t* __restrict__ W,
    const float* __restrict__ bias0, const float* __restrict__ bias1,
    int K, float* __restrict__ outF, bf16_t* __restrict__ outB,
    int ldo, int permute)
{
    __shared__ bf16_t As[128 * GLDP];
    __shared__ bf16_t Bs[128 * GLDP];
    const int tid = threadIdx.x;
    const int lane = tid & 63;
    const int wid = tid >> 6;
    const int q = lane >> 4, l15 = lane & 15;
    const int wr = (wid >> 1) * 64, wc = (wid & 1) * 64;
    const size_t br = (size_t)blockIdx.y * 128;
    const size_t bc = (size_t)blockIdx.x * 128;

    const int r0 = tid >> 2;
    const int r1 = r0 + 64;
    const int k0 = (tid & 3) * 8;

    f32x4 acc[4][4] = {};

    for (int kt = 0; kt < K; kt += 32) {
        bf16x8 a0 = *(const bf16x8*)(A + (br + r0) * K + kt + k0);
        bf16x8 a1 = *(const bf16x8*)(A + (br + r1) * K + kt + k0);
        bf16x8 w0 = *(const bf16x8*)(W + (bc + r0) * K + kt + k0);
        bf16x8 w1 = *(const bf16x8*)(W + (bc + r1) * K + kt + k0);
        if (kt) __syncthreads();
        *(bf16x8*)(As + r0 * GLDP + k0) = a0;
        *(bf16x8*)(As + r1 * GLDP + k0) = a1;
        *(bf16x8*)(Bs + r0 * GLDP + k0) = w0;
        *(bf16x8*)(Bs + r1 * GLDP + k0) = w1;
        __syncthreads();
        bf16x8 bfr[4];
        #pragma unroll
        for (int j = 0; j < 4; ++j)
            bfr[j] = *(const bf16x8*)(Bs + (wc + j * 16 + l15) * GLDP + q * 8);
        #pragma unroll
        for (int i = 0; i < 4; ++i) {
            bf16x8 afr = *(const bf16x8*)(As + (wr + i * 16 + l15) * GLDP + q * 8);
            #pragma unroll
            for (int j = 0; j < 4; ++j)
                acc[i][j] = __builtin_amdgcn_mfma_f32_16x16x32_bf16(afr, bfr[j], acc[i][j], 0, 0, 0);
        }
    }

    #pragma unroll
    for (int j = 0; j < 4; ++j) {
        int col = (int)bc + wc + j * 16 + l15;
        float bv = bias0[col];
        if (bias1) bv += bias1[col];
        #pragma unroll
        for (int i = 0; i < 4; ++i) {
            int rowb = (int)br + wr + i * 16 + q * 4;
            #pragma unroll
            for (int rr = 0; rr < 4; ++rr) {
                int row = rowb + rr;
                float v = acc[i][j][rr] + bv;
                if (outF) {
                    int orow = permute ? ((row & 63) * T_LEN + (row >> 6)) : row;
                    outF[(size_t)orow * ldo + col] = v;
                } else {
                    outB[(size_t)row * ldo + col] = (bf16_t)v;
                }
            }
        }
    }
}

// ---------------- persistent bidirectional LSTM layer ----------------
// grid: 256 blocks (dir = bid>>7, jb = bid&127), 256 threads:
//   b = tid&63, jj = (tid>>6)&1, kh = tid>>7 (K-split half).
// Thread (kh=0) owns state (c) for (dir, b, j=jb*2+jj). Grid-wide step sync via
// per-dir monotone counters + agent-scope fences (256 blocks <= 256 CUs -> co-resident).
// hall layout: [dir][t][kp=128][b=64][2] bf16 (pair of j=2kp, 2kp+1).
__global__ __launch_bounds__(256) void lstm_layer_kernel(
    const float* __restrict__ xgf, const float* __restrict__ xgb,   // [NTB][1024]
    const float* __restrict__ Whhf, const float* __restrict__ Whhb, // [1024][256]
    bf16_t* __restrict__ hall,
    unsigned int* __restrict__ ctr)  // [2 dir][64]
{
    __shared__ unsigned int hsU[128 * 64];   // 32 KB: [kp][b] bf16-pair as u32
    __shared__ float ws[8 * 256];            // 8 KB: [(g*2+jj)][k]
    __shared__ float part[4 * 128];          // 2 KB: [g][jj*64+b]
    const int tid = threadIdx.x;
    const int dir = blockIdx.x >> 7;
    const int jb  = blockIdx.x & 127;
    const int b  = tid & 63;
    const int jj = (tid >> 6) & 1;
    const int kh = tid >> 7;
    const int j = jb * 2 + jj;
    const float* xg  = dir ? xgb : xgf;
    const float* Whh = dir ? Whhb : Whhf;
    unsigned int* myctr = ctr + dir * 64;
    bf16_t* hdir = hall + (size_t)dir * 96 * 16384;

    // preload this block's 8 weight rows (4 gates x 2 j) into LDS
    #pragma unroll
    for (int i = 0; i < 8; ++i) {
        int g = i >> 1, jw = i & 1;
        ws[i * 256 + tid] = Whh[((size_t)(g * 256 + jb * 2 + jw) << 8) + tid];
    }

    const int kbase = kh * 32;   // float4-granule k range [kbase, kbase+32)
    float c = 0.f;
    for (int s = 0; s < 96; ++s) {
        const int t = dir ? (95 - s) : s;
        float a0 = 0.f, a1 = 0.f, a2 = 0.f, a3 = 0.f;
        if (kh == 0) {
            const float* xr = xg + ((size_t)(t * 64 + b) << 10) + j;
            a0 = xr[0]; a1 = xr[256]; a2 = xr[512]; a3 = xr[768];
        }
        if (s > 0) {
            const int tprev = dir ? t + 1 : t - 1;
            if (tid == 0) {
                const unsigned target = 128u * (unsigned)s;
                while (__hip_atomic_load(myctr, __ATOMIC_RELAXED, __HIP_MEMORY_SCOPE_AGENT) < target)
                    __builtin_amdgcn_s_sleep(16);
            }
            __syncthreads();
            __builtin_amdgcn_fence(__ATOMIC_ACQUIRE, "agent");
            // stage h_{s-1} (bf16 pairs) into LDS, 32 KB straight copy
            const uint4* src = (const uint4*)(hdir + (size_t)tprev * 16384);
            uint4* dst = (uint4*)hsU;
            #pragma unroll
            for (int i = 0; i < 8; ++i) dst[i * 256 + tid] = src[i * 256 + tid];
            __syncthreads();
            const float4* wsv = (const float4*)ws;
            #pragma unroll 4
            for (int q = kbase; q < kbase + 32; ++q) {
                unsigned p0 = hsU[(2 * q) * 64 + b];
                unsigned p1 = hsU[(2 * q + 1) * 64 + b];
                float h0 = __uint_as_float(p0 << 16);
                float h1 = __uint_as_float(p0 & 0xffff0000u);
                float h2 = __uint_as_float(p1 << 16);
                float h3 = __uint_as_float(p1 & 0xffff0000u);
                float4 w0 = wsv[(0 * 2 + jj) * 64 + q];
                float4 w1 = wsv[(1 * 2 + jj) * 64 + q];
                float4 w2 = wsv[(2 * 2 + jj) * 64 + q];
                float4 w3 = wsv[(3 * 2 + jj) * 64 + q];
                a0 += h0 * w0.x + h1 * w0.y + h2 * w0.z + h3 * w0.w;
                a1 += h0 * w1.x + h1 * w1.y + h2 * w1.z + h3 * w1.w;
                a2 += h0 * w2.x + h1 * w2.y + h2 * w2.z + h3 * w2.w;
                a3 += h0 * w3.x + h1 * w3.y + h2 * w3.z + h3 * w3.w;
            }
            if (kh) {
                part[0 * 128 + jj * 64 + b] = a0;
                part[1 * 128 + jj * 64 + b] = a1;
                part[2 * 128 + jj * 64 + b] = a2;
                part[3 * 128 + jj * 64 + b] = a3;
            }
            __syncthreads();
            if (!kh) {
                a0 += part[0 * 128 + jj * 64 + b];
                a1 += part[1 * 128 + jj * 64 + b];
                a2 += part[2 * 128 + jj * 64 + b];
                a3 += part[3 * 128 + jj * 64 + b];
            }
        }
        if (!kh) {
            float iv = sigmoidf_(a0), fv = sigmoidf_(a1);
            float gv = tanhf(a2), ov = sigmoidf_(a3);
            c = (s == 0) ? (iv * gv) : (fv * c + iv * gv);
            float h = ov * tanhf(c);
            hdir[(size_t)t * 16384 + jb * 128 + b * 2 + jj] = (bf16_t)h;
        }
        if (s < 95) {
            __syncthreads();   // drains all waves' hall stores (vmcnt 0) before arrival
            if (tid == 0) {
                __builtin_amdgcn_fence(__ATOMIC_RELEASE, "agent");
                __hip_atomic_fetch_add(myctr, 1u, __ATOMIC_RELAXED, __HIP_MEMORY_SCOPE_AGENT);
            }
        }
    }
}

// ---------------- hall -> dense row-major output ----------------
// grid (96, 2). layer0: outB = h0b bf16 [(t*64+b)][512] ; layer1: outF fp32 rows b*96+t, ld 1536.
__global__ __launch_bounds__(256) void h_transpose_kernel(
    const bf16_t* __restrict__ hall, bf16_t* __restrict__ outB, float* __restrict__ outF)
{
    __shared__ unsigned int tileU[8192];  // 32 KB: one (dir,t) slab [kp][b]
    const int t = blockIdx.x, dir = blockIdx.y;
    const unsigned int* src = (const unsigned int*)(hall + ((size_t)dir * 96 + t) * 16384);
    #pragma unroll
    for (int i = 0; i < 32; ++i) tileU[i * 256 + threadIdx.x] = src[i * 256 + threadIdx.x];
    __syncthreads();
    const int b = threadIdx.x >> 2, seg = threadIdx.x & 3;   // cols seg*64 .. seg*64+63
    if (outB) {
        bf16_t* orow = outB + (size_t)(t * 64 + b) * 512 + dir * 256 + seg * 64;
        #pragma unroll
        for (int j0 = 0; j0 < 64; j0 += 8) {
            int kp = (seg * 64 + j0) >> 1;
            uint4 v;
            v.x = tileU[(kp + 0) * 64 + b];
            v.y = tileU[(kp + 1) * 64 + b];
            v.z = tileU[(kp + 2) * 64 + b];
            v.w = tileU[(kp + 3) * 64 + b];
            *(uint4*)(orow + j0) = v;
        }
    } else {
        float* orow = outF + (size_t)(b * 96 + t) * 1536 + dir * 256 + seg * 64;
        #pragma unroll
        for (int j0 = 0; j0 < 64; j0 += 2) {
            int kp = (seg * 64 + j0) >> 1;
            unsigned p = tileU[kp * 64 + b];
            float2 v;
            v.x = __uint_as_float(p << 16);
            v.y = __uint_as_float(p & 0xffff0000u);
            *(float2*)(orow + j0) = v;
        }
    }
}

// ---------------- host ----------------
extern "C" void kernel_launch(void* const* d_in, const int* in_sizes, int n_in,
                              void* d_out, int out_size, void* d_ws, size_t ws_size,
                              hipStream_t stream)
{
    const float* r1 = (const float*)d_in[0];
    const float* r2 = (const float*)d_in[1];
    const float* r3 = (const float*)d_in[2];
    const float* r4 = (const float*)d_in[3];
    const float* U_a = (const float*)d_in[4];
    const float* U_v = (const float*)d_in[5];
    const float* W_a = (const float*)d_in[7];
    const float* b_a = (const float*)d_in[8];
    const float* W_v = (const float*)d_in[9];
    const float* b_v = (const float*)d_in[10];
    const float* W_l = (const float*)d_in[11];
    const float* b_l = (const float*)d_in[12];
    const float* Wih0f = (const float*)d_in[13];
    const float* Whh0f = (const float*)d_in[14];
    const float* bih0f = (const float*)d_in[15];
    const float* bhh0f = (const float*)d_in[16];
    const float* Wih0b = (const float*)d_in[17];
    const float* Whh0b = (const float*)d_in[18];
    const float* bih0b = (const float*)d_in[19];
    const float* bhh0b = (const float*)d_in[20];
    const float* Wih1f = (const float*)d_in[21];
    const float* Whh1f = (const float*)d_in[22];
    const float* bih1f = (const float*)d_in[23];
    const float* bhh1f = (const float*)d_in[24];
    const float* Wih1b = (const float*)d_in[25];
    const float* Whh1b = (const float*)d_in[26];
    const float* bih1b = (const float*)d_in[27];
    const float* bhh1b = (const float*)d_in[28];
    float* out = (float*)d_out;

    char* wsb = (char*)d_ws;
    size_t off = 0;
    auto alloc = [&](size_t bytes) -> void* {
        void* p = wsb + off;
        off = (off + bytes + 255) & ~(size_t)255;
        return p;
    };
    float*  stats   = (float*)alloc(512 * sizeof(float));
    bf16_t* Ub      = (bf16_t*)alloc((size_t)NTB * 1024 * 2);
    bf16_t* Uab     = (bf16_t*)alloc((size_t)NTB * 128 * 2);
    bf16_t* Wab     = (bf16_t*)alloc((size_t)512 * 128 * 2);
    bf16_t* Uvb     = (bf16_t*)alloc((size_t)NTB * 512 * 2);
    bf16_t* Wvb     = (bf16_t*)alloc((size_t)512 * 512 * 2);
    bf16_t* Wlb     = (bf16_t*)alloc((size_t)512 * 1024 * 2);
    bf16_t* Wih0fb  = (bf16_t*)alloc((size_t)1024 * 512 * 2);
    bf16_t* Wih0bb  = (bf16_t*)alloc((size_t)1024 * 512 * 2);
    bf16_t* Wih1fb  = (bf16_t*)alloc((size_t)1024 * 512 * 2);
    bf16_t* Wih1bb  = (bf16_t*)alloc((size_t)1024 * 512 * 2);
    bf16_t* Ulb     = (bf16_t*)alloc((size_t)NTB * 512 * 2);
    bf16_t* h0b     = (bf16_t*)alloc((size_t)NTB * 512 * 2);
    float*  xgf     = (float*)alloc((size_t)NTB * 1024 * 4);
    float*  xgb     = (float*)alloc((size_t)NTB * 1024 * 4);
    bf16_t* hall0   = (bf16_t*)alloc((size_t)2 * 96 * 16384 * 2);
    bf16_t* hall1   = (bf16_t*)alloc((size_t)2 * 96 * 16384 * 2);
    unsigned int* ctr = (unsigned int*)alloc(256 * sizeof(unsigned int)); // 2 layers x 2 dirs x 64

    hipMemsetAsync(ctr, 0, 256 * sizeof(unsigned int), stream);

    // LN2 + U
    ln_stats_kernel<<<256, 256, 0, stream>>>(r1, r2, r3, r4, stats);
    compute_u_kernel<<<NTB * 1024 / 4 / 256, 256, 0, stream>>>(r1, r2, r3, r4, stats, Ub);

    // bf16 staging casts
    cast_pad_kernel<<<NTB * 128 / 256, 256, 0, stream>>>(U_a, Uab, NTB, 100, 128);
    cast_pad_kernel<<<512 * 128 / 256, 256, 0, stream>>>(W_a, Wab, 512, 100, 128);
    cast_pad_kernel<<<NTB * 512 / 256, 256, 0, stream>>>(U_v, Uvb, NTB, 512, 512);
    cast_pad_kernel<<<512 * 512 / 256, 256, 0, stream>>>(W_v, Wvb, 512, 512, 512);
    cast_pad_kernel<<<512 * 1024 / 256, 256, 0, stream>>>(W_l, Wlb, 512, 1024, 1024);
    cast_pad_kernel<<<1024 * 512 / 256, 256, 0, stream>>>(Wih0f, Wih0fb, 1024, 512, 512);
    cast_pad_kernel<<<1024 * 512 / 256, 256, 0, stream>>>(Wih0b, Wih0bb, 1024, 512, 512);
    cast_pad_kernel<<<1024 * 512 / 256, 256, 0, stream>>>(Wih1f, Wih1fb, 1024, 512, 512);
    cast_pad_kernel<<<1024 * 512 / 256, 256, 0, stream>>>(Wih1b, Wih1bb, 1024, 512, 512);

    // emotions_a -> out[:, 0:512] ; emotions_v -> out[:, 512:1024]
    gemm_bt_kernel<<<dim3(4, 48), 256, 0, stream>>>(Uab, Wab, b_a, nullptr, 128, out, nullptr, 1536, 1);
    gemm_bt_kernel<<<dim3(4, 48), 256, 0, stream>>>(Uvb, Wvb, b_v, nullptr, 512, out + 512, nullptr, 1536, 1);
    // Ul (bf16, feeds layer0 projections)
    gemm_bt_kernel<<<dim3(4, 48), 256, 0, stream>>>(Ub, Wlb, b_l, nullptr, 1024, nullptr, Ulb, 512, 0);
    // layer0 input projections
    gemm_bt_kernel<<<dim3(8, 48), 256, 0, stream>>>(Ulb, Wih0fb, bih0f, bhh0f, 512, xgf, nullptr, 1024, 0);
    gemm_bt_kernel<<<dim3(8, 48), 256, 0, stream>>>(Ulb, Wih0bb, bih0b, bhh0b, 512, xgb, nullptr, 1024, 0);
    // layer0 recurrence (persistent, one launch)
    lstm_layer_kernel<<<256, 256, 0, stream>>>(xgf, xgb, Whh0f, Whh0b, hall0, ctr);
    h_transpose_kernel<<<dim3(96, 2), 256, 0, stream>>>(hall0, h0b, nullptr);
    // layer1 input projections
    gemm_bt_kernel<<<dim3(8, 48), 256, 0, stream>>>(h0b, Wih1fb, bih1f, bhh1f, 512, xgf, nullptr, 1024, 0);
    gemm_bt_kernel<<<dim3(8, 48), 256, 0, stream>>>(h0b, Wih1bb, bih1b, bhh1b, 512, xgb, nullptr, 1024, 0);
    // layer1 recurrence -> hall1 -> out[:, 1024:1536]
    lstm_layer_kernel<<<256, 256, 0, stream>>>(xgf, xgb, Whh1f, Whh1b, hall1, ctr + 128);
    h_transpose_kernel<<<dim3(96, 2), 256, 0, stream>>>(hall1, nullptr, out + 1024);
}

// Round 3
// 1540.375 us; speedup vs baseline: 2.7795x; 2.7795x over previous
//
#include <hip/hip_runtime.h>
#include <hip/hip_bf16.h>
#include <cstddef>

typedef __bf16 bf16_t;
typedef __bf16 bf16x8 __attribute__((ext_vector_type(8)));
typedef __bf16 bf16x4 __attribute__((ext_vector_type(4)));
typedef float f32x4 __attribute__((ext_vector_type(4)));

#define T_LEN 96
#define BATCH 64
#define DM 1024
#define NTB 6144  // T*B

__device__ __forceinline__ float sigmoidf_(float x) { return 1.0f / (1.0f + expf(-x)); }

// ---------------- LN2 stats: per (tensor i, batch b) mean & inv-std over T*DM ----------------
__global__ __launch_bounds__(256) void ln_stats_kernel(
    const float* __restrict__ r1, const float* __restrict__ r2,
    const float* __restrict__ r3, const float* __restrict__ r4,
    float* __restrict__ stats)  // [4*64][2]
{
    const int i = blockIdx.x >> 6, b = blockIdx.x & 63;
    const float* r = (i == 0) ? r1 : (i == 1) ? r2 : (i == 2) ? r3 : r4;
    float s = 0.f, ss = 0.f;
    for (int t = 0; t < T_LEN; ++t) {
        float4 v = ((const float4*)(r + (size_t)(t * BATCH + b) * DM))[threadIdx.x];
        s  += v.x + v.y + v.z + v.w;
        ss += v.x * v.x + v.y * v.y + v.z * v.z + v.w * v.w;
    }
    __shared__ float sh[512];
    sh[threadIdx.x] = s; sh[256 + threadIdx.x] = ss;
    __syncthreads();
    for (int off = 128; off > 0; off >>= 1) {
        if (threadIdx.x < off) {
            sh[threadIdx.x] += sh[threadIdx.x + off];
            sh[256 + threadIdx.x] += sh[256 + threadIdx.x + off];
        }
        __syncthreads();
    }
    if (threadIdx.x == 0) {
        const float inv = 1.0f / (float)(T_LEN * DM);
        float mean = sh[0] * inv;
        float var  = sh[256] * inv - mean * mean;
        stats[blockIdx.x * 2 + 0] = mean;
        stats[blockIdx.x * 2 + 1] = rsqrtf(var + 1e-5f);
    }
}

// ---------------- U = mean of 4 normalized tensors, written as bf16 [NTB,1024] ----------------
__global__ __launch_bounds__(256) void compute_u_kernel(
    const float* __restrict__ r1, const float* __restrict__ r2,
    const float* __restrict__ r3, const float* __restrict__ r4,
    const float* __restrict__ stats, bf16_t* __restrict__ U)
{
    const int idx4 = blockIdx.x * 256 + threadIdx.x;   // over NTB*1024/4
    const int b = (idx4 >> 8) & 63;
    const float m0 = stats[(0 * 64 + b) * 2], s0 = stats[(0 * 64 + b) * 2 + 1];
    const float m1 = stats[(1 * 64 + b) * 2], s1 = stats[(1 * 64 + b) * 2 + 1];
    const float m2 = stats[(2 * 64 + b) * 2], s2 = stats[(2 * 64 + b) * 2 + 1];
    const float m3 = stats[(3 * 64 + b) * 2], s3 = stats[(3 * 64 + b) * 2 + 1];
    float4 a = ((const float4*)r1)[idx4];
    float4 c = ((const float4*)r2)[idx4];
    float4 d = ((const float4*)r3)[idx4];
    float4 e = ((const float4*)r4)[idx4];
    bf16x4 o;
    o[0] = (bf16_t)(0.25f * ((a.x - m0) * s0 + (c.x - m1) * s1 + (d.x - m2) * s2 + (e.x - m3) * s3));
    o[1] = (bf16_t)(0.25f * ((a.y - m0) * s0 + (c.y - m1) * s1 + (d.y - m2) * s2 + (e.y - m3) * s3));
    o[2] = (bf16_t)(0.25f * ((a.z - m0) * s0 + (c.z - m1) * s1 + (d.z - m2) * s2 + (e.z - m3) * s3));
    o[3] = (bf16_t)(0.25f * ((a.w - m0) * s0 + (c.w - m1) * s1 + (d.w - m2) * s2 + (e.w - m3) * s3));
    ((bf16x4*)U)[idx4] = o;
}

// ---------------- f32 -> bf16 cast with optional K padding ----------------
__global__ __launch_bounds__(256) void cast_pad_kernel(
    const float* __restrict__ src, bf16_t* __restrict__ dst,
    int rows, int K, int Kpad)
{
    int idx = blockIdx.x * 256 + threadIdx.x;
    if (idx >= rows * Kpad) return;
    int r = idx / Kpad;
    int k = idx - r * Kpad;
    float v = (k < K) ? src[(size_t)r * K + k] : 0.f;
    dst[idx] = (bf16_t)v;
}

// ---------------- Whh fp32 [1024][256] -> per-block bf16 frag layout [16 jb][64 n][256 k] ----------------
// n = g*16 + jj  <->  weight row g*256 + jb*16 + jj
__global__ __launch_bounds__(256) void wr_pack_kernel(
    const float* __restrict__ whh, bf16_t* __restrict__ dst)
{
    int i = blockIdx.x * 256 + threadIdx.x;   // 16*64*256 = 262144
    int k = i & 255, n = (i >> 8) & 63, bid = i >> 14;
    int srow = (n >> 4) * 256 + bid * 16 + (n & 15);
    dst[i] = (bf16_t)whh[srow * 256 + k];
}

// ---------------- bf16 MFMA GEMM: C[M,N] = A[M,K] @ W[N,K]^T + bias ----------------
// mode 0: outB bf16 row-major ldo.  mode 1: outF fp32, rows permuted (b*96+t), ldo.
// mode 2: outF fp32 in xg-packed layout [jb=(n>>4)&15][t][b][g*16+jj], g=n>>8, jj=n&15.
#define GLDP 40  // LDS row pitch in bf16 (32 + 8 pad)
__global__ __launch_bounds__(256) void gemm_bt_kernel(
    const bf16_t* __restrict__ A, const bf16_t* __restrict__ W,
    const float* __restrict__ bias0, const float* __restrict__ bias1,
    int K, float* __restrict__ outF, bf16_t* __restrict__ outB,
    int ldo, int mode)
{
    __shared__ bf16_t As[128 * GLDP];
    __shared__ bf16_t Bs[128 * GLDP];
    const int tid = threadIdx.x;
    const int lane = tid & 63;
    const int wid = tid >> 6;
    const int q = lane >> 4, l15 = lane & 15;
    const int wr = (wid >> 1) * 64, wc = (wid & 1) * 64;
    const size_t br = (size_t)blockIdx.y * 128;
    const size_t bc = (size_t)blockIdx.x * 128;

    const int r0 = tid >> 2;
    const int r1 = r0 + 64;
    const int k0 = (tid & 3) * 8;

    f32x4 acc[4][4] = {};

    for (int kt = 0; kt < K; kt += 32) {
        bf16x8 a0 = *(const bf16x8*)(A + (br + r0) * K + kt + k0);
        bf16x8 a1 = *(const bf16x8*)(A + (br + r1) * K + kt + k0);
        bf16x8 w0 = *(const bf16x8*)(W + (bc + r0) * K + kt + k0);
        bf16x8 w1 = *(const bf16x8*)(W + (bc + r1) * K + kt + k0);
        if (kt) __syncthreads();
        *(bf16x8*)(As + r0 * GLDP + k0) = a0;
        *(bf16x8*)(As + r1 * GLDP + k0) = a1;
        *(bf16x8*)(Bs + r0 * GLDP + k0) = w0;
        *(bf16x8*)(Bs + r1 * GLDP + k0) = w1;
        __syncthreads();
        bf16x8 bfr[4];
        #pragma unroll
        for (int j = 0; j < 4; ++j)
            bfr[j] = *(const bf16x8*)(Bs + (wc + j * 16 + l15) * GLDP + q * 8);
        #pragma unroll
        for (int i = 0; i < 4; ++i) {
            bf16x8 afr = *(const bf16x8*)(As + (wr + i * 16 + l15) * GLDP + q * 8);
            #pragma unroll
            for (int j = 0; j < 4; ++j)
                acc[i][j] = __builtin_amdgcn_mfma_f32_16x16x32_bf16(afr, bfr[j], acc[i][j], 0, 0, 0);
        }
    }

    #pragma unroll
    for (int j = 0; j < 4; ++j) {
        int col = (int)bc + wc + j * 16 + l15;
        float bv = bias0[col];
        if (bias1) bv += bias1[col];
        #pragma unroll
        for (int i = 0; i < 4; ++i) {
            int rowb = (int)br + wr + i * 16 + q * 4;
            #pragma unroll
            for (int rr = 0; rr < 4; ++rr) {
                int row = rowb + rr;
                float v = acc[i][j][rr] + bv;
                if (mode == 0) {
                    outB[(size_t)row * ldo + col] = (bf16_t)v;
                } else if (mode == 1) {
                    int orow = (row & 63) * T_LEN + (row >> 6);
                    outF[(size_t)orow * ldo + col] = v;
                } else {
                    int t = row >> 6, b = row & 63;
                    int g = col >> 8, jb = (col >> 4) & 15, jj = col & 15;
                    outF[((((size_t)jb * 96 + t) * 64 + b) << 6) + g * 16 + jj] = v;
                }
            }
        }
    }
}

// ---------------- persistent bidirectional LSTM layer (flag-sync version) ----------------
// grid: 32 blocks: dir = bid>>4, jb = bid&15. 256 threads = 4 waves.
// Block computes a [64 b x 64 n] gate tile (n = g*16+jj, j = jb*16+jj) via MFMA over K=256.
// c-state in registers. Sync: per-block flag stores + 16-lane poll (no RMW contention).
// hall: [96 t][64 b][512] bf16, cols = dir*256 + j  (== layer-1 GEMM input & output layout).
__global__ __launch_bounds__(256) void lstm_layer2_kernel(
    const float* __restrict__ xgpf, const float* __restrict__ xgpb,   // [16][96][64][64] fp32
    const bf16_t* __restrict__ wrbf, const bf16_t* __restrict__ wrbb, // [16][64][256] bf16
    bf16_t* __restrict__ hall,
    unsigned int* __restrict__ flags)  // [2 dir][16]
{
    __shared__ bf16_t hA[64 * 264];   // 33 KB  h_prev [b][k] pitch 264
    __shared__ bf16_t wB[64 * 264];   // 33 KB  weights [n][k] pitch 264
    __shared__ float  xs[64 * 68];    // 17 KB  xg slice [b][64] pitch 68
    const int tid = threadIdx.x;
    const int dir = blockIdx.x >> 4, jb = blockIdx.x & 15;
    const int w = tid >> 6, lane = tid & 63, q = lane >> 4, l15 = lane & 15;
    const float* xgp = dir ? xgpb : xgpf;
    const bf16_t* wrb = dir ? wrbb : wrbf;
    unsigned int* fl = flags + dir * 16;

    const int srow = tid >> 2, sq = tid & 3;   // staging: row 0..63, quarter 0..3

    // load this block's weight tile 32 KB -> wB (used from s=1; barrier below covers)
    {
        const bf16_t* src = wrb + (((size_t)jb * 64 + srow) << 8) + sq * 64;
        bf16_t* dst = wB + srow * 264 + sq * 64;
        #pragma unroll
        for (int i = 0; i < 8; ++i)
            *(uint4*)(dst + i * 8) = *(const uint4*)(src + i * 8);
    }

    float cst[4] = {0.f, 0.f, 0.f, 0.f};

    for (int s = 0; s < 96; ++s) {
        const int t = dir ? (95 - s) : s;
        // prefetch xg slice into registers (independent of flags)
        float4 xr[4];
        {
            const float* src = xgp + ((((size_t)jb * 96 + t) * 64 + srow) << 6) + sq * 16;
            #pragma unroll
            for (int i = 0; i < 4; ++i) xr[i] = ((const float4*)src)[i];
        }
        if (s > 0) {
            if (tid < 16) {
                while (__hip_atomic_load(&fl[tid], __ATOMIC_RELAXED, __HIP_MEMORY_SCOPE_AGENT) < (unsigned)s)
                    __builtin_amdgcn_s_sleep(1);
            }
            __syncthreads();
            __builtin_amdgcn_fence(__ATOMIC_ACQUIRE, "agent");
        }
        // stage xg
        {
            float* dst = xs + srow * 68 + sq * 16;
            #pragma unroll
            for (int i = 0; i < 4; ++i) ((float4*)dst)[i] = xr[i];
        }
        f32x4 acc[4] = {};
        if (s > 0) {
            const int tprev = dir ? t + 1 : t - 1;
            // stage h_prev (this dir's half): 32 KB
            const bf16_t* src = hall + (((size_t)tprev * 64 + srow) << 9) + dir * 256 + sq * 64;
            bf16_t* dst = hA + srow * 264 + sq * 64;
            #pragma unroll
            for (int i = 0; i < 8; ++i)
                *(uint4*)(dst + i * 8) = *(const uint4*)(src + i * 8);
            __syncthreads();
            const bf16_t* aRow = hA + (w * 16 + l15) * 264 + q * 8;
            #pragma unroll
            for (int kc = 0; kc < 8; ++kc) {
                bf16x8 af = *(const bf16x8*)(aRow + kc * 32);
                #pragma unroll
                for (int ct = 0; ct < 4; ++ct) {
                    bf16x8 bf = *(const bf16x8*)(wB + (ct * 16 + l15) * 264 + q * 8 + kc * 32);
                    acc[ct] = __builtin_amdgcn_mfma_f32_16x16x32_bf16(af, bf, acc[ct], 0, 0, 0);
                }
            }
        } else {
            __syncthreads();
        }
        // gates + state update + h write
        #pragma unroll
        for (int r = 0; r < 4; ++r) {
            const int b = w * 16 + q * 4 + r;
            const float* xrow = xs + b * 68 + l15;
            float ai = acc[0][r] + xrow[0];
            float af_ = acc[1][r] + xrow[16];
            float ag = acc[2][r] + xrow[32];
            float ao = acc[3][r] + xrow[48];
            float iv = sigmoidf_(ai), fv = sigmoidf_(af_);
            float gv = tanhf(ag), ov = sigmoidf_(ao);
            cst[r] = (s == 0) ? (iv * gv) : (fv * cst[r] + iv * gv);
            float h = ov * tanhf(cst[r]);
            hall[(((size_t)t * 64 + b) << 9) + dir * 256 + jb * 16 + l15] = (bf16_t)h;
        }
        __syncthreads();   // all waves' global h stores drained (vmcnt 0 before barrier)
        if (tid == 0) {
            __builtin_amdgcn_fence(__ATOMIC_RELEASE, "agent");
            __hip_atomic_store(&fl[jb], (unsigned)(s + 1), __ATOMIC_RELAXED, __HIP_MEMORY_SCOPE_AGENT);
        }
    }
}

// ---------------- hall (layer1) -> fp32 output columns ----------------
__global__ __launch_bounds__(256) void out_expand_kernel(
    const bf16_t* __restrict__ hall, float* __restrict__ out)  // out pre-offset to col 1024
{
    const int t = blockIdx.x;
    const int b = threadIdx.x >> 2, seg = threadIdx.x & 3;
    const bf16_t* src = hall + (((size_t)t * 64 + b) << 9) + seg * 128;
    float* dst = out + ((size_t)b * 96 + t) * 1536 + seg * 128;
    #pragma unroll
    for (int i = 0; i < 16; ++i) {
        bf16x8 v = ((const bf16x8*)src)[i];
        float4 lo, hi;
        lo.x = (float)v[0]; lo.y = (float)v[1]; lo.z = (float)v[2]; lo.w = (float)v[3];
        hi.x = (float)v[4]; hi.y = (float)v[5]; hi.z = (float)v[6]; hi.w = (float)v[7];
        ((float4*)dst)[2 * i]     = lo;
        ((float4*)dst)[2 * i + 1] = hi;
    }
}

// ---------------- host ----------------
extern "C" void kernel_launch(void* const* d_in, const int* in_sizes, int n_in,
                              void* d_out, int out_size, void* d_ws, size_t ws_size,
                              hipStream_t stream)
{
    const float* r1 = (const float*)d_in[0];
    const float* r2 = (const float*)d_in[1];
    const float* r3 = (const float*)d_in[2];
    const float* r4 = (const float*)d_in[3];
    const float* U_a = (const float*)d_in[4];
    const float* U_v = (const float*)d_in[5];
    const float* W_a = (const float*)d_in[7];
    const float* b_a = (const float*)d_in[8];
    const float* W_v = (const float*)d_in[9];
    const float* b_v = (const float*)d_in[10];
    const float* W_l = (const float*)d_in[11];
    const float* b_l = (const float*)d_in[12];
    const float* Wih0f = (const float*)d_in[13];
    const float* Whh0f = (const float*)d_in[14];
    const float* bih0f = (const float*)d_in[15];
    const float* bhh0f = (const float*)d_in[16];
    const float* Wih0b = (const float*)d_in[17];
    const float* Whh0b = (const float*)d_in[18];
    const float* bih0b = (const float*)d_in[19];
    const float* bhh0b = (const float*)d_in[20];
    const float* Wih1f = (const float*)d_in[21];
    const float* Whh1f = (const float*)d_in[22];
    const float* bih1f = (const float*)d_in[23];
    const float* bhh1f = (const float*)d_in[24];
    const float* Wih1b = (const float*)d_in[25];
    const float* Whh1b = (const float*)d_in[26];
    const float* bih1b = (const float*)d_in[27];
    const float* bhh1b = (const float*)d_in[28];
    float* out = (float*)d_out;

    char* wsb = (char*)d_ws;
    size_t off = 0;
    auto alloc = [&](size_t bytes) -> void* {
        void* p = wsb + off;
        off = (off + bytes + 255) & ~(size_t)255;
        return p;
    };
    float*  stats   = (float*)alloc(512 * sizeof(float));
    bf16_t* Ub      = (bf16_t*)alloc((size_t)NTB * 1024 * 2);
    bf16_t* Uab     = (bf16_t*)alloc((size_t)NTB * 128 * 2);
    bf16_t* Wab     = (bf16_t*)alloc((size_t)512 * 128 * 2);
    bf16_t* Uvb     = (bf16_t*)alloc((size_t)NTB * 512 * 2);
    bf16_t* Wvb     = (bf16_t*)alloc((size_t)512 * 512 * 2);
    bf16_t* Wlb     = (bf16_t*)alloc((size_t)512 * 1024 * 2);
    bf16_t* Wih0fb  = (bf16_t*)alloc((size_t)1024 * 512 * 2);
    bf16_t* Wih0bb  = (bf16_t*)alloc((size_t)1024 * 512 * 2);
    bf16_t* Wih1fb  = (bf16_t*)alloc((size_t)1024 * 512 * 2);
    bf16_t* Wih1bb  = (bf16_t*)alloc((size_t)1024 * 512 * 2);
    bf16_t* Ulb     = (bf16_t*)alloc((size_t)NTB * 512 * 2);
    float*  xgpf    = (float*)alloc((size_t)NTB * 1024 * 4);
    float*  xgpb    = (float*)alloc((size_t)NTB * 1024 * 4);
    bf16_t* wrb0f   = (bf16_t*)alloc((size_t)16 * 64 * 256 * 2);
    bf16_t* wrb0b   = (bf16_t*)alloc((size_t)16 * 64 * 256 * 2);
    bf16_t* wrb1f   = (bf16_t*)alloc((size_t)16 * 64 * 256 * 2);
    bf16_t* wrb1b   = (bf16_t*)alloc((size_t)16 * 64 * 256 * 2);
    bf16_t* hall0   = (bf16_t*)alloc((size_t)96 * 64 * 512 * 2);
    bf16_t* hall1   = (bf16_t*)alloc((size_t)96 * 64 * 512 * 2);
    unsigned int* flags = (unsigned int*)alloc(256 * sizeof(unsigned int));

    hipMemsetAsync(flags, 0, 256 * sizeof(unsigned int), stream);

    // LN2 + U
    ln_stats_kernel<<<256, 256, 0, stream>>>(r1, r2, r3, r4, stats);
    compute_u_kernel<<<NTB * 1024 / 4 / 256, 256, 0, stream>>>(r1, r2, r3, r4, stats, Ub);

    // bf16 staging casts
    cast_pad_kernel<<<NTB * 128 / 256, 256, 0, stream>>>(U_a, Uab, NTB, 100, 128);
    cast_pad_kernel<<<512 * 128 / 256, 256, 0, stream>>>(W_a, Wab, 512, 100, 128);
    cast_pad_kernel<<<NTB * 512 / 256, 256, 0, stream>>>(U_v, Uvb, NTB, 512, 512);
    cast_pad_kernel<<<512 * 512 / 256, 256, 0, stream>>>(W_v, Wvb, 512, 512, 512);
    cast_pad_kernel<<<512 * 1024 / 256, 256, 0, stream>>>(W_l, Wlb, 512, 1024, 1024);
    cast_pad_kernel<<<1024 * 512 / 256, 256, 0, stream>>>(Wih0f, Wih0fb, 1024, 512, 512);
    cast_pad_kernel<<<1024 * 512 / 256, 256, 0, stream>>>(Wih0b, Wih0bb, 1024, 512, 512);
    cast_pad_kernel<<<1024 * 512 / 256, 256, 0, stream>>>(Wih1f, Wih1fb, 1024, 512, 512);
    cast_pad_kernel<<<1024 * 512 / 256, 256, 0, stream>>>(Wih1b, Wih1bb, 1024, 512, 512);

    // Whh frag repacks (one-time)
    wr_pack_kernel<<<1024, 256, 0, stream>>>(Whh0f, wrb0f);
    wr_pack_kernel<<<1024, 256, 0, stream>>>(Whh0b, wrb0b);
    wr_pack_kernel<<<1024, 256, 0, stream>>>(Whh1f, wrb1f);
    wr_pack_kernel<<<1024, 256, 0, stream>>>(Whh1b, wrb1b);

    // emotions_a -> out[:, 0:512] ; emotions_v -> out[:, 512:1024]  (mode 1: permuted rows)
    gemm_bt_kernel<<<dim3(4, 48), 256, 0, stream>>>(Uab, Wab, b_a, nullptr, 128, out, nullptr, 1536, 1);
    gemm_bt_kernel<<<dim3(4, 48), 256, 0, stream>>>(Uvb, Wvb, b_v, nullptr, 512, out + 512, nullptr, 1536, 1);
    // Ul (bf16)
    gemm_bt_kernel<<<dim3(4, 48), 256, 0, stream>>>(Ub, Wlb, b_l, nullptr, 1024, nullptr, Ulb, 512, 0);
    // layer0 input projections -> packed xg (mode 2)
    gemm_bt_kernel<<<dim3(8, 48), 256, 0, stream>>>(Ulb, Wih0fb, bih0f, bhh0f, 512, xgpf, nullptr, 0, 2);
    gemm_bt_kernel<<<dim3(8, 48), 256, 0, stream>>>(Ulb, Wih0bb, bih0b, bhh0b, 512, xgpb, nullptr, 0, 2);
    // layer0 recurrence
    lstm_layer2_kernel<<<32, 256, 0, stream>>>(xgpf, xgpb, wrb0f, wrb0b, hall0, flags);
    // layer1 input projections (A = hall0 == [6144][512] bf16)
    gemm_bt_kernel<<<dim3(8, 48), 256, 0, stream>>>(hall0, Wih1fb, bih1f, bhh1f, 512, xgpf, nullptr, 0, 2);
    gemm_bt_kernel<<<dim3(8, 48), 256, 0, stream>>>(hall0, Wih1bb, bih1b, bhh1b, 512, xgpb, nullptr, 0, 2);
    // layer1 recurrence
    lstm_layer2_kernel<<<32, 256, 0, stream>>>(xgpf, xgpb, wrb1f, wrb1b, hall1, flags + 64);
    // final fp32 expand -> out[:, 1024:1536]
    out_expand_kernel<<<96, 256, 0, stream>>>(hall1, out + 1024);
}